// Round 19
// baseline (2060.915 us; speedup 1.0000x reference)
//
#include <hip/hip_runtime.h>
#include <hip/hip_bf16.h>
#include <math.h>

#define LK 72      // conv LDS row stride (bf16) for BK=64: 144B rows

typedef __hip_bfloat16 bf16;
typedef __bf16 bf16x8 __attribute__((ext_vector_type(8)));
typedef __bf16 bf16x4v __attribute__((ext_vector_type(4)));
typedef float  f32x4  __attribute__((ext_vector_type(4)));

// ---------------------------------------------------------------------------
// PE table TRANSPOSED: peT[d][l], d<256, l<1600.
__global__ __launch_bounds__(256)
void pe_init_kernel(float* __restrict__ peT) {
    const int d = blockIdx.x;
    const int j = d >> 1;
    const double dv = exp(-(double)(2 * j) * 9.210340371976184 / 256.0); // ln(1e4)
    for (int l = threadIdx.x; l < 1600; l += 256) {
        const float arg = (float)l * (float)dv;
        peT[(size_t)d * 1600 + l] = (d & 1) ? cosf(arg) : sinf(arg);
    }
}

// ---------------------------------------------------------------------------
// Repack conv weight fp32 [256][Cin][ksq] -> bf16 [ksq][256][Cin].
__global__ void repack_w(const float* __restrict__ w, __bf16* __restrict__ dst,
                         int Cin, int ksq)
{
    const int total = 256 * Cin * ksq;
    const int idx = blockIdx.x * 256 + threadIdx.x;
    if (idx >= total) return;
    const int o = idx / (Cin * ksq);
    const int r = idx - o * (Cin * ksq);
    const int c = r / ksq;
    const int sh = r - c * ksq;
    dst[((size_t)sh * 256 + o) * Cin + c] = (__bf16)w[idx];
}

// ---------------------------------------------------------------------------
// SPE = support lateral + PE (bf16): spe[sb][c][l] = s[sb][c][l] + peT[c][l]
__global__ void addpe_kernel(const bf16* __restrict__ s, const float* __restrict__ peT,
                             bf16* __restrict__ spe, int L, int total)
{
    const int idx = blockIdx.x * 256 + threadIdx.x;
    if (idx >= total) return;
    const int l = idx % L;
    const int c = (idx / L) & 255;
    spe[idx] = __float2bfloat16(__bfloat162float(s[idx]) + peT[(size_t)c * 1600 + l]);
}

// ---------------------------------------------------------------------------
__global__ void bias_init_kernel(float* __restrict__ out, const float* __restrict__ bias,
                                 int N, int total)
{
    const int idx = blockIdx.x * 256 + threadIdx.x;
    if (idx >= total) return;
    out[idx] = bias[(idx / N) & 255];
}

__global__ void cast_f32_bf16(const float* __restrict__ src, bf16* __restrict__ dst,
                              int total)
{
    const int idx = blockIdx.x * 256 + threadIdx.x;
    if (idx < total) dst[idx] = __float2bfloat16(src[idx]);
}

// ---------------------------------------------------------------------------
// 1x1 GEMM (MFMA). out_mode: 0 = f32 d-major, 1 = bf16 d-major, 2 = bf16 row-major.
__global__ __launch_bounds__(256)
void gemm1x1_mfma(const void* __restrict__ in, const __bf16* __restrict__ wbf,
                  const float* __restrict__ bias, void* __restrict__ out,
                  int Cin, int N, int in_bf16, int out_mode)
{
    const int b  = blockIdx.z;
    const int o0 = blockIdx.y * 64;
    const int n0 = blockIdx.x * 64;
    const int t  = threadIdx.x;
    const int wv  = t >> 6;
    const int ln  = t & 63;
    const int lm  = ln & 15;
    const int kq8 = (ln >> 4) * 8;

    __shared__ __bf16 Bs[64][LK];

    f32x4 acc[4];
    #pragma unroll
    for (int ct = 0; ct < 4; ++ct) acc[ct] = (f32x4){0.f, 0.f, 0.f, 0.f};

    const int cg = t >> 4;
    const int ng = t & 15;
    const int nb = n0 + ng * 4;
    const bool vec_ok = ((N & 3) == 0) && (nb + 3 < N);

    const float*  inf = (const float*)in;
    const __bf16* inh = (const __bf16*)in;
    const size_t inb0 = (size_t)b * Cin * N;

    const __bf16* arow = wbf + (size_t)(o0 + wv * 16 + lm) * Cin;

    for (int c0 = 0; c0 < Cin; c0 += 64) {
        __syncthreads();
        float rv[4][4];
        #pragma unroll
        for (int i = 0; i < 4; ++i) {
            const int c = c0 + cg * 4 + i;
            const size_t base = inb0 + (size_t)c * N + nb;
            if (vec_ok) {
                if (in_bf16) {
                    const bf16x4v v = *(const bf16x4v*)&inh[base];
                    rv[i][0] = (float)v[0]; rv[i][1] = (float)v[1];
                    rv[i][2] = (float)v[2]; rv[i][3] = (float)v[3];
                } else {
                    const float4 v = *(const float4*)&inf[base];
                    rv[i][0] = v.x; rv[i][1] = v.y; rv[i][2] = v.z; rv[i][3] = v.w;
                }
            } else {
                #pragma unroll
                for (int jj = 0; jj < 4; ++jj) {
                    const int n = nb + jj;
                    rv[i][jj] = (n < N) ? (in_bf16 ? (float)inh[inb0 + (size_t)c * N + n]
                                                   : inf[inb0 + (size_t)c * N + n])
                                        : 0.f;
                }
            }
        }
        #pragma unroll
        for (int jj = 0; jj < 4; ++jj) {
            bf16x4v pk;
            pk[0] = (__bf16)rv[0][jj]; pk[1] = (__bf16)rv[1][jj];
            pk[2] = (__bf16)rv[2][jj]; pk[3] = (__bf16)rv[3][jj];
            *(bf16x4v*)&Bs[ng * 4 + jj][cg * 4] = pk;
        }
        __syncthreads();

        #pragma unroll
        for (int k0 = 0; k0 < 64; k0 += 32) {
            const bf16x8 a = *(const bf16x8*)&arow[c0 + k0 + kq8];
            #pragma unroll
            for (int ct = 0; ct < 4; ++ct) {
                const bf16x8 bb = *(const bf16x8*)&Bs[ct * 16 + lm][k0 + kq8];
                acc[ct] = __builtin_amdgcn_mfma_f32_16x16x32_bf16(a, bb, acc[ct], 0, 0, 0);
            }
        }
    }

    const int rbase = o0 + wv * 16 + (ln >> 4) * 4;
    #pragma unroll
    for (int ct = 0; ct < 4; ++ct) {
        const int col = n0 + ct * 16 + lm;
        if (col < N) {
            if (out_mode == 2) {
                bf16x4v pk;
                #pragma unroll
                for (int r = 0; r < 4; ++r)
                    pk[r] = (__bf16)(acc[ct][r] + bias[rbase + r]);
                *(bf16x4v*)&((__bf16*)out)[((size_t)b * N + col) * 256 + rbase] = pk;
            } else {
                const size_t outb = (size_t)b * 256 * N;
                #pragma unroll
                for (int r = 0; r < 4; ++r) {
                    const int o = rbase + r;
                    const float val = acc[ct][r] + bias[o];
                    if (out_mode == 1) ((__bf16*)out)[outb + (size_t)o * N + col] = (__bf16)val;
                    else               ((float*)out)[outb + (size_t)o * N + col] = val;
                }
            }
        }
    }
}

// ---------------------------------------------------------------------------
// 3x3 stride-1 pad-1 conv (MFMA) with HALO tile.
__global__ __launch_bounds__(256)
void conv3x3h_mfma(const void* __restrict__ in, const __bf16* __restrict__ wbf,
                   const float* __restrict__ bias, void* __restrict__ out,
                   const float* __restrict__ addup,
                   int Cin, int H, int W, int in_bf16, int out_bf16)
{
    const int b  = blockIdx.z;
    const int o0 = blockIdx.y * 64;
    const int n0 = blockIdx.x * 64;
    const int N  = H * W;
    const int EXT = 64 + 2 * W + 2;
    const int t  = threadIdx.x;
    const int wv = t >> 6;
    const int ln = t & 63;
    const int lm = ln & 15;
    const int kq8 = (ln >> 4) * 8;

    __shared__ __bf16 Bs[146][LK];

    f32x4 acc[4];
    #pragma unroll
    for (int ct = 0; ct < 4; ++ct) acc[ct] = (f32x4){0.f, 0.f, 0.f, 0.f};

    const size_t inb0 = (size_t)b * Cin * N;
    const int upH = H >> 1, upW = W >> 1;
    const float* addb = addup ? addup + (size_t)b * Cin * upH * upW : nullptr;
    const float*  inf = (const float*)in;
    const __bf16* inh = (const __bf16*)in;

    int yct[4], xct[4];
    bool nok[4];
    #pragma unroll
    for (int ct = 0; ct < 4; ++ct) {
        const int n = n0 + ct * 16 + lm;
        nok[ct] = n < N;
        yct[ct] = nok[ct] ? n / W : 0;
        xct[ct] = nok[ct] ? n - yct[ct] * W : 0;
    }

    bf16x8 zro;
    #pragma unroll
    for (int j = 0; j < 8; ++j) zro[j] = (__bf16)0.f;

    const int srow = t & 63;
    const int kb16 = (t >> 6) * 16;
    const int basep = n0 - W - 1;

    for (int c0 = 0; c0 < Cin; c0 += 64) {
        __syncthreads();
        for (int rb = 0; rb < EXT; rb += 64) {
            const int row = rb + srow;
            if (row < EXT) {
                const int p = basep + row;
                const bool ok = (p >= 0) && (p < N);
                const int py = ok ? p / W : 0;
                const int px = ok ? p - py * W : 0;
                #pragma unroll
                for (int j = 0; j < 16; ++j) {
                    const int kk = kb16 + j;
                    const int c  = c0 + kk;
                    float v = 0.f;
                    if (ok) {
                        v = in_bf16 ? (float)inh[inb0 + (size_t)c * N + p]
                                    : inf[inb0 + (size_t)c * N + p];
                        if (addb) v += addb[((size_t)c * upH + (py >> 1)) * upW + (px >> 1)];
                    }
                    Bs[row][kk] = (__bf16)v;
                }
            }
        }
        __syncthreads();

        #pragma unroll
        for (int sh = 0; sh < 9; ++sh) {
            const int ky = sh / 3, kx = sh - ky * 3;
            const int off = (ky - 1) * W + (kx - 1) + W + 1;
            bool vm[4];
            #pragma unroll
            for (int ct = 0; ct < 4; ++ct)
                vm[ct] = nok[ct] && (unsigned)(yct[ct] + ky - 1) < (unsigned)H
                                 && (unsigned)(xct[ct] + kx - 1) < (unsigned)W;
            const __bf16* ash = wbf + ((size_t)sh * 256 + o0 + wv * 16 + lm) * Cin + c0;
            #pragma unroll
            for (int k0 = 0; k0 < 64; k0 += 32) {
                const bf16x8 a = *(const bf16x8*)&ash[k0 + kq8];
                #pragma unroll
                for (int ct = 0; ct < 4; ++ct) {
                    bf16x8 bb = *(const bf16x8*)&Bs[ct * 16 + lm + off][k0 + kq8];
                    bb = vm[ct] ? bb : zro;
                    acc[ct] = __builtin_amdgcn_mfma_f32_16x16x32_bf16(a, bb, acc[ct], 0, 0, 0);
                }
            }
        }
    }

    const size_t outb = (size_t)b * 256 * N;
    const int rbase = o0 + wv * 16 + (ln >> 4) * 4;
    #pragma unroll
    for (int ct = 0; ct < 4; ++ct) {
        const int col = n0 + ct * 16 + lm;
        if (col < N) {
            #pragma unroll
            for (int r = 0; r < 4; ++r) {
                const int o = rbase + r;
                const float val = acc[ct][r] + bias[o];
                if (out_bf16) ((__bf16*)out)[outb + (size_t)o * N + col] = (__bf16)val;
                else          ((float*)out)[outb + (size_t)o * N + col] = val;
            }
        }
    }
}

// ---------------------------------------------------------------------------
// Split-K, batch-packed conv (tiny-N / huge-K: P6, P7).
__global__ __launch_bounds__(256)
void convsk_mfma(const void* __restrict__ in, const __bf16* __restrict__ wbf,
                 float* __restrict__ out,
                 int B, int Cin, int Hin, int Win, int Ho, int Wo,
                 int ks, int stride, int pad, int relu_in, int in_bf16,
                 int kchunk)
{
    const int N  = Ho * Wo;
    const int NT = B * N;
    const int col0 = blockIdx.x * 64;
    const int t  = threadIdx.x;
    const int wv = t >> 6;
    const int ln = t & 63;
    const int lm = ln & 15;
    const int kq8 = (ln >> 4) * 8;

    __shared__ __bf16 Bs[64][LK];

    f32x4 acc[4][4];
    #pragma unroll
    for (int rt = 0; rt < 4; ++rt)
        #pragma unroll
        for (int ct = 0; ct < 4; ++ct) acc[rt][ct] = (f32x4){0.f, 0.f, 0.f, 0.f};

    const size_t inHW = (size_t)Hin * Win;
    const int ksq = ks * ks;
    const float*  inf = (const float*)in;
    const __bf16* inh = (const __bf16*)in;

    const int srow = t & 63;
    const int kb16 = (t >> 6) * 16;
    const int scol = col0 + srow;
    const bool cvalid = scol < NT;
    int sb = 0, yo = 0, xo = 0;
    if (cvalid) {
        sb = scol / N;
        const int sn = scol - sb * N;
        yo = sn / Wo; xo = sn - yo * Wo;
    }

    const int Ktot = Cin * ksq;
    const int kbeg = blockIdx.y * kchunk;
    const int kend = min(kbeg + kchunk, Ktot);

    for (int k0 = kbeg; k0 < kend; k0 += 64) {
        const int sh = k0 / Cin;
        const int c0 = k0 - sh * Cin;
        const int ky = sh / ks, kx = sh - ky * ks;
        const int iy = yo * stride + ky - pad;
        const int ix = xo * stride + kx - pad;
        const bool ld_ok = cvalid && iy >= 0 && iy < Hin && ix >= 0 && ix < Win;
        const size_t sidx = (size_t)sb * Cin * inHW + (size_t)iy * Win + ix;

        __syncthreads();
        #pragma unroll
        for (int j = 0; j < 16; ++j) {
            const int kk = kb16 + j;
            const int c  = c0 + kk;
            float v = 0.f;
            if (ld_ok) {
                v = in_bf16 ? (float)inh[sidx + (size_t)c * inHW]
                            : inf[sidx + (size_t)c * inHW];
                if (relu_in) v = fmaxf(v, 0.f);
            }
            Bs[srow][kk] = (__bf16)v;
        }
        __syncthreads();

        #pragma unroll
        for (int k32 = 0; k32 < 64; k32 += 32) {
            bf16x8 bfr[4];
            #pragma unroll
            for (int ct = 0; ct < 4; ++ct)
                bfr[ct] = *(const bf16x8*)&Bs[ct * 16 + lm][k32 + kq8];
            #pragma unroll
            for (int rt = 0; rt < 4; ++rt) {
                const __bf16* ap = wbf + ((size_t)sh * 256 + wv * 64 + rt * 16 + lm) * Cin
                                       + c0 + k32 + kq8;
                const bf16x8 a = *(const bf16x8*)ap;
                #pragma unroll
                for (int ct = 0; ct < 4; ++ct)
                    acc[rt][ct] = __builtin_amdgcn_mfma_f32_16x16x32_bf16(a, bfr[ct],
                                                                          acc[rt][ct], 0, 0, 0);
            }
        }
    }

    const int rb0 = wv * 64 + (ln >> 4) * 4;
    #pragma unroll
    for (int ct = 0; ct < 4; ++ct) {
        const int col = col0 + ct * 16 + lm;
        if (col < NT) {
            const int be = col / N;
            const int ne = col - be * N;
            float* ob = out + (size_t)be * 256 * N + ne;
            #pragma unroll
            for (int rt = 0; rt < 4; ++rt)
                #pragma unroll
                for (int r = 0; r < 4; ++r)
                    atomicAdd(&ob[(size_t)(rb0 + rt * 16 + r) * N], acc[rt][ct][r]);
        }
    }
}

// ---------------------------------------------------------------------------
__global__ void add_up_kernel(const float* __restrict__ a, const float* __restrict__ up,
                              float* __restrict__ o, int H, int W, int total)
{
    const int idx = blockIdx.x * 256 + threadIdx.x;
    if (idx >= total) return;
    const int x = idx % W;
    const int tmp = idx / W;
    const int y = tmp % H;
    const int bc = tmp / H;
    o[idx] = a[idx] + up[((size_t)bc * (H >> 1) + (y >> 1)) * (W >> 1) + (x >> 1)];
}

// ---------------------------------------------------------------------------
// MFMA flash attention — r14 configuration + s_setprio(1) around MFMA clusters
// (T5: helps attn with independent blocks at different phases; NULL on GEMM).
__global__ __launch_bounds__(256)
void attn_mfma(const __bf16* __restrict__ Qrow, const __bf16* __restrict__ Krow,
               const bf16* __restrict__ Sv, float* __restrict__ outp, int L, int S)
{
    const int b  = blockIdx.y;
    const int s  = blockIdx.z;
    const int q0 = blockIdx.x * 64;
    const int t  = threadIdx.x;
    const int wv = t >> 6;
    const int ln = t & 63;
    const int lm = ln & 15;
    const int lg = ln >> 4;

    __shared__ __bf16 Ks[32][264];
    __shared__ __bf16 Vt[256][40];
    __shared__ __bf16 Pl[4][16][40];

    bf16x8 qf[8];
    {
        const int q = q0 + wv * 16 + lm;
        if (q < L) {
            const __bf16* qp = Qrow + ((size_t)b * L + q) * 256 + lg * 8;
            #pragma unroll
            for (int sl = 0; sl < 8; ++sl) qf[sl] = *(const bf16x8*)&qp[sl * 32];
        } else {
            #pragma unroll
            for (int sl = 0; sl < 8; ++sl)
                #pragma unroll
                for (int j = 0; j < 8; ++j) qf[sl][j] = (__bf16)0.f;
        }
    }

    f32x4 acc[16];
    #pragma unroll
    for (int ds = 0; ds < 16; ++ds) acc[ds] = (f32x4){0.f, 0.f, 0.f, 0.f};
    float m_run[4] = {-INFINITY, -INFINITY, -INFINITY, -INFINITY};
    float l_run[4] = {0.f, 0.f, 0.f, 0.f};

    const size_t kbase = (size_t)(b * S + s) * L * 256;
    const __bf16* vb0  = (const __bf16*)Sv + (size_t)(b * S + s) * 256 * L;

    const int nt = (L + 31) >> 5;
    for (int lt = 0; lt < nt; ++lt) {
        const int l0 = lt << 5;
        __syncthreads();
        {
            const int row = t >> 3, cb = (t & 7) * 32;
            const int l = l0 + row;
            if (l < L) {
                const __bf16* src = Krow + kbase + (size_t)l * 256 + cb;
                #pragma unroll
                for (int j = 0; j < 4; ++j)
                    *(bf16x8*)&Ks[row][cb + j * 8] = *(const bf16x8*)&src[j * 8];
            } else {
                #pragma unroll
                for (int j = 0; j < 32; ++j) Ks[row][cb + j] = (__bf16)0.f;
            }
        }
        {
            const __bf16* src = vb0 + (size_t)t * L + l0;
            if (l0 + 32 <= L && ((((size_t)src) & 15) == 0)) {
                #pragma unroll
                for (int j = 0; j < 4; ++j)
                    *(bf16x8*)&Vt[t][j * 8] = *(const bf16x8*)&src[j * 8];
            } else {
                #pragma unroll
                for (int j = 0; j < 32; ++j)
                    Vt[t][j] = (l0 + j < L) ? src[j] : (__bf16)0.f;
            }
        }
        __syncthreads();

        f32x4 sc0 = (f32x4){0.f, 0.f, 0.f, 0.f};
        f32x4 sc1 = (f32x4){0.f, 0.f, 0.f, 0.f};
        __builtin_amdgcn_s_setprio(1);
        #pragma unroll
        for (int sl = 0; sl < 8; ++sl) {
            const bf16x8 k0 = *(const bf16x8*)&Ks[lm][sl * 32 + lg * 8];
            const bf16x8 k1 = *(const bf16x8*)&Ks[16 + lm][sl * 32 + lg * 8];
            sc0 = __builtin_amdgcn_mfma_f32_16x16x32_bf16(qf[sl], k0, sc0, 0, 0, 0);
            sc1 = __builtin_amdgcn_mfma_f32_16x16x32_bf16(qf[sl], k1, sc1, 0, 0, 0);
        }
        __builtin_amdgcn_s_setprio(0);

        const bool v0 = (l0 + lm) < L;
        const bool v1 = (l0 + 16 + lm) < L;
        float p0[4], p1[4], mt[4];
        #pragma unroll
        for (int r = 0; r < 4; ++r) {
            const float a = v0 ? sc0[r] * 0.0625f : -INFINITY;
            const float c = v1 ? sc1[r] * 0.0625f : -INFINITY;
            p0[r] = a; p1[r] = c; mt[r] = fmaxf(a, c);
        }
        #pragma unroll
        for (int w = 1; w < 16; w <<= 1)
            #pragma unroll
            for (int r = 0; r < 4; ++r) mt[r] = fmaxf(mt[r], __shfl_xor(mt[r], w, 16));
        float alpha[4], rs[4];
        #pragma unroll
        for (int r = 0; r < 4; ++r) {
            const float mn = fmaxf(m_run[r], mt[r]);
            alpha[r] = __expf(m_run[r] - mn);
            p0[r] = v0 ? __expf(p0[r] - mn) : 0.f;
            p1[r] = v1 ? __expf(p1[r] - mn) : 0.f;
            m_run[r] = mn;
            rs[r] = p0[r] + p1[r];
        }
        #pragma unroll
        for (int w = 1; w < 16; w <<= 1)
            #pragma unroll
            for (int r = 0; r < 4; ++r) rs[r] += __shfl_xor(rs[r], w, 16);
        #pragma unroll
        for (int r = 0; r < 4; ++r) l_run[r] = l_run[r] * alpha[r] + rs[r];
        #pragma unroll
        for (int ds = 0; ds < 16; ++ds)
            #pragma unroll
            for (int r = 0; r < 4; ++r) acc[ds][r] *= alpha[r];

        #pragma unroll
        for (int r = 0; r < 4; ++r) {
            Pl[wv][lg * 4 + r][lm]      = (__bf16)p0[r];
            Pl[wv][lg * 4 + r][16 + lm] = (__bf16)p1[r];
        }
        const bf16x8 pa = *(const bf16x8*)&Pl[wv][lm][lg * 8];

        __builtin_amdgcn_s_setprio(1);
        #pragma unroll
        for (int ds = 0; ds < 16; ++ds) {
            const bf16x8 vv = *(const bf16x8*)&Vt[ds * 16 + lm][lg * 8];
            acc[ds] = __builtin_amdgcn_mfma_f32_16x16x32_bf16(pa, vv, acc[ds], 0, 0, 0);
        }
        __builtin_amdgcn_s_setprio(0);
    }

    const int qrow = q0 + wv * 16 + lg * 4;
    float inv[4];
    #pragma unroll
    for (int r = 0; r < 4; ++r) inv[r] = 1.f / (l_run[r] * (float)S);
    #pragma unroll
    for (int ds = 0; ds < 16; ++ds) {
        const int d = ds * 16 + lm;
        float* ob = outp + ((size_t)b * 512 + 256 + d) * L;
        #pragma unroll
        for (int r = 0; r < 4; ++r) {
            const int q = qrow + r;
            if (q < L) atomicAdd(&ob[q], acc[ds][r] * inv[r]);
        }
    }
}

// ---------------------------------------------------------------------------
__global__ void zero_attn_half(float* __restrict__ outp, int L, int total)
{
    const int idx = blockIdx.x * 256 + threadIdx.x;
    if (idx >= total) return;
    const int b = idx / (256 * L);
    const int r = idx - b * 256 * L;
    outp[((size_t)b * 512 + 256) * L + r] = 0.f;
}

// ---------------------------------------------------------------------------
__global__ void copy_cast_kernel(const void* __restrict__ src, float* __restrict__ dst,
                                 int HW, int total, int in_bf16)
{
    const int idx = blockIdx.x * 256 + threadIdx.x;
    if (idx >= total) return;
    const int b = idx / (256 * HW);
    const int r = idx - b * 256 * HW;
    const float v = in_bf16 ? __bfloat162float(((const bf16*)src)[idx])
                            : ((const float*)src)[idx];
    dst[(size_t)b * 512 * HW + r] = v;
}

// ---------------------------------------------------------------------------
extern "C" void kernel_launch(void* const* d_in, const int* in_sizes, int n_in,
                              void* d_out, int out_size, void* d_ws, size_t ws_size,
                              hipStream_t stream)
{
    (void)in_sizes; (void)n_in; (void)out_size; (void)ws_size;
    const float* C3 = (const float*)d_in[0];
    const float* C4 = (const float*)d_in[1];
    const float* C5 = (const float*)d_in[2];
    const float* S3 = (const float*)d_in[3];
    const float* S4 = (const float*)d_in[4];
    const float* S5 = (const float*)d_in[5];
    const float* p31w = (const float*)d_in[6];  const float* p31b = (const float*)d_in[7];
    const float* p32w = (const float*)d_in[8];  const float* p32b = (const float*)d_in[9];
    const float* p41w = (const float*)d_in[10]; const float* p41b = (const float*)d_in[11];
    const float* p42w = (const float*)d_in[12]; const float* p42b = (const float*)d_in[13];
    const float* p51w = (const float*)d_in[14]; const float* p51b = (const float*)d_in[15];
    const float* p52w = (const float*)d_in[16]; const float* p52b = (const float*)d_in[17];
    const float* p6w  = (const float*)d_in[18]; const float* p6b  = (const float*)d_in[19];
    const float* p7w  = (const float*)d_in[20]; const float* p7b  = (const float*)d_in[21];
    const float* qw   = (const float*)d_in[22]; const float* qb   = (const float*)d_in[23];
    const float* kw   = (const float*)d_in[24]; const float* kb   = (const float*)d_in[25];
    float* out = (float*)d_out;

    // ---- workspace layout (bytes, 256B-aligned). ~165 MB.
    uint8_t* base = (uint8_t*)d_ws;
    size_t off = 0;
    auto A = [&](size_t bytes) { size_t r = off; off += (bytes + 255) & ~(size_t)255; return r; };
    float* pPE  = (float*)(base + A((size_t)256 * 1600 * 4));           // peT[d][l]
    bf16*  pP3q = (bf16*) (base + A((size_t)8  * 256 * 1600 * 2));
    float* pP4q = (float*)(base + A((size_t)8  * 256 * 400  * 4));
    float* pP5q = (float*)(base + A((size_t)8  * 256 * 100  * 4));
    bf16*  pP3s = (bf16*) (base + A((size_t)40 * 256 * 1600 * 2));
    bf16*  pP4s = (bf16*) (base + A((size_t)40 * 256 * 400  * 2));
    bf16*  pP5s = (bf16*) (base + A((size_t)40 * 256 * 100  * 2));
    float* pP6q = (float*)(base + A((size_t)8  * 256 * 25   * 4));
    float* pP7q = (float*)(base + A((size_t)8  * 256 * 9    * 4));
    float* pP6sF= (float*)(base + A((size_t)40 * 256 * 25   * 4));
    float* pP7sF= (float*)(base + A((size_t)40 * 256 * 9    * 4));
    bf16*  pP6s = (bf16*) (base + A((size_t)40 * 256 * 25   * 2));
    bf16*  pP7s = (bf16*) (base + A((size_t)40 * 256 * 9    * 2));
    float* pP4m = (float*)(base + A((size_t)8  * 256 * 400  * 4));
    float* pP5f = (float*)(base + A((size_t)8  * 256 * 100  * 4));
    float* pP4f = (float*)(base + A((size_t)8  * 256 * 400  * 4));
    bf16*  pP3f = (bf16*) (base + A((size_t)8  * 256 * 1600 * 2));
    __bf16* pQ  = (__bf16*)(base + A((size_t)8  * 1600 * 256 * 2));   // row-major [b][q][256]
    __bf16* pK  = (__bf16*)(base + A((size_t)40 * 1600 * 256 * 2));   // row-major [sb][l][256]
    bf16*  pSPE = (bf16*) (base + A((size_t)40 * 256 * 1600 * 2));    // d-major
    __bf16* r31 = (__bf16*)(base + A((size_t)256 * 512 * 2));
    __bf16* r32 = (__bf16*)(base + A((size_t)256 * 256 * 9 * 2));
    __bf16* r41 = (__bf16*)(base + A((size_t)256 * 1024 * 2));
    __bf16* r42 = (__bf16*)(base + A((size_t)256 * 256 * 9 * 2));
    __bf16* r51 = (__bf16*)(base + A((size_t)256 * 2048 * 2));
    __bf16* r52 = (__bf16*)(base + A((size_t)256 * 256 * 9 * 2));
    __bf16* r6  = (__bf16*)(base + A((size_t)256 * 2048 * 9 * 2));
    __bf16* r7  = (__bf16*)(base + A((size_t)256 * 256 * 9 * 2));
    __bf16* rq  = (__bf16*)(base + A((size_t)256 * 256 * 2));
    __bf16* rk  = (__bf16*)(base + A((size_t)256 * 256 * 2));

    pe_init_kernel<<<dim3(256), dim3(256), 0, stream>>>(pPE);

    auto rep = [&](const float* w, __bf16* dst, int Cin, int ksq) {
        const int total = 256 * Cin * ksq;
        repack_w<<<dim3((total + 255) / 256), dim3(256), 0, stream>>>(w, dst, Cin, ksq);
    };
    rep(p31w, r31, 512, 1);  rep(p32w, r32, 256, 9);
    rep(p41w, r41, 1024, 1); rep(p42w, r42, 256, 9);
    rep(p51w, r51, 2048, 1); rep(p52w, r52, 256, 9);
    rep(p6w,  r6,  2048, 9); rep(p7w,  r7,  256, 9);
    rep(qw,   rq,  256, 1);  rep(kw,   rk,  256, 1);

    auto g1 = [&](const void* in, const __bf16* wbf, const float* bias, void* o,
                  int B, int Cin, int N, int in_bf16, int out_mode) {
        dim3 g((N + 63) / 64, 4, B);
        gemm1x1_mfma<<<g, dim3(256), 0, stream>>>(in, wbf, bias, o, Cin, N,
                                                  in_bf16, out_mode);
    };
    auto ch3 = [&](const void* in, const __bf16* wbf, const float* bias, void* o,
                   int B, int Cin, int H, int W, const float* addup,
                   int in_bf16, int out_bf16) {
        const int N = H * W;
        dim3 g((N + 63) / 64, 4, B);
        conv3x3h_mfma<<<g, dim3(256), 0, stream>>>(in, wbf, bias, o, addup,
                                                   Cin, H, W, in_bf16, out_bf16);
    };
    auto csk = [&](const void* in, const __bf16* wbf, const float* bias, float* o,
                   int B, int Cin, int Hin, int Win, int Ho, int Wo,
                   int stride, int pad, int relu_in, int in_bf16, int kchunk) {
        const int N = Ho * Wo;
        const int NT = B * N;
        const int Ktot = Cin * 9;
        const int total = B * 256 * N;
        bias_init_kernel<<<dim3((total + 255) / 256), dim3(256), 0, stream>>>(
            o, bias, N, total);
        dim3 g((NT + 63) / 64, (Ktot + kchunk - 1) / kchunk, 1);
        convsk_mfma<<<g, dim3(256), 0, stream>>>(in, wbf, o, B, Cin, Hin, Win, Ho, Wo,
                                                 3, stride, pad, relu_in, in_bf16, kchunk);
    };

    // lateral 1x1 convs
    g1(C3, r31, p31b, pP3q, 8,  512,  1600, 0, 1);
    g1(C4, r41, p41b, pP4q, 8,  1024, 400,  0, 0);
    g1(C5, r51, p51b, pP5q, 8,  2048, 100,  0, 0);
    g1(S3, r31, p31b, pP3s, 40, 512,  1600, 0, 1);
    g1(S4, r41, p41b, pP4s, 40, 1024, 400,  0, 1);
    g1(S5, r51, p51b, pP5s, 40, 2048, 100,  0, 1);
    // P6 / P7 via split-K packed kernel
    csk(C5,    r6, p6b, pP6q,  8,  2048, 10, 10, 5, 5, 2, 1, 0, 0, 576);
    csk(S5,    r6, p6b, pP6sF, 40, 2048, 10, 10, 5, 5, 2, 1, 0, 0, 1152);
    {
        const int t6 = 40 * 256 * 25;
        cast_f32_bf16<<<dim3((t6 + 255) / 256), dim3(256), 0, stream>>>(pP6sF, pP6s, t6);
    }
    csk(pP6q,  r7, p7b, pP7q,  8,  256, 5, 5, 3, 3, 2, 1, 1, 0, 576);
    csk(pP6sF, r7, p7b, pP7sF, 40, 256, 5, 5, 3, 3, 2, 1, 1, 0, 576);
    {
        const int t7 = 40 * 256 * 9;
        cast_f32_bf16<<<dim3((t7 + 255) / 256), dim3(256), 0, stream>>>(pP7sF, pP7s, t7);
    }
    // top-down
    {
        const int total = 8 * 256 * 400;
        add_up_kernel<<<dim3((total + 255) / 256), dim3(256), 0, stream>>>(
            pP4q, pP5q, pP4m, 20, 20, total);
    }
    ch3(pP5q, r52, p52b, pP5f, 8, 256, 10, 10, nullptr, 0, 0);
    ch3(pP4m, r42, p42b, pP4f, 8, 256, 20, 20, nullptr, 0, 0);
    ch3(pP3q, r32, p32b, pP3f, 8, 256, 40, 40, pP4m, 1, 1);

    const int Ls[5] = {1600, 400, 100, 25, 9};
    const void* qsrc[5] = {pP3f, pP4f, pP5f, pP6q, pP7q};
    const int   qbf [5] = {1, 0, 0, 0, 0};
    const bf16* ssrc[5] = {pP3s, pP4s, pP5s, pP6s, pP7s};
    size_t ooff[5];
    {
        size_t ao = 0;
        for (int i = 0; i < 5; ++i) { ooff[i] = ao; ao += (size_t)8 * 512 * Ls[i]; }
    }
    for (int i = 0; i < 5; ++i) {
        const int L = Ls[i];
        const int stotal = 40 * 256 * L;
        addpe_kernel<<<dim3((stotal + 255) / 256), dim3(256), 0, stream>>>(
            ssrc[i], pPE, pSPE, L, stotal);
        g1(qsrc[i], rq, qb, pQ, 8, 256, L, qbf[i], 2);
        g1(pSPE, rk, kb, pK, 40, 256, L, 1, 2);
        const int total = 8 * 256 * L;
        zero_attn_half<<<dim3((total + 255) / 256), dim3(256), 0, stream>>>(
            out + ooff[i], L, total);
        attn_mfma<<<dim3((L + 63) / 64, 8, 5), dim3(256), 0, stream>>>(
            pQ, pK, pSPE, out + ooff[i], L, 5);
        copy_cast_kernel<<<dim3((total + 255) / 256), dim3(256), 0, stream>>>(
            qsrc[i], out + ooff[i], L, total, qbf[i]);
    }
}

// Round 20
// 2051.591 us; speedup vs baseline: 1.0045x; 1.0045x over previous
//
#include <hip/hip_runtime.h>
#include <hip/hip_bf16.h>
#include <math.h>

#define LK 72      // conv LDS row stride (bf16) for BK=64: 144B rows

typedef __hip_bfloat16 bf16;
typedef __bf16 bf16x8 __attribute__((ext_vector_type(8)));
typedef __bf16 bf16x4v __attribute__((ext_vector_type(4)));
typedef float  f32x4  __attribute__((ext_vector_type(4)));

// ---------------------------------------------------------------------------
// PE table TRANSPOSED: peT[d][l], d<256, l<1600.
__global__ __launch_bounds__(256)
void pe_init_kernel(float* __restrict__ peT) {
    const int d = blockIdx.x;
    const int j = d >> 1;
    const double dv = exp(-(double)(2 * j) * 9.210340371976184 / 256.0); // ln(1e4)
    for (int l = threadIdx.x; l < 1600; l += 256) {
        const float arg = (float)l * (float)dv;
        peT[(size_t)d * 1600 + l] = (d & 1) ? cosf(arg) : sinf(arg);
    }
}

// ---------------------------------------------------------------------------
// Repack conv weight fp32 [256][Cin][ksq] -> bf16 [ksq][256][Cin].
__global__ void repack_w(const float* __restrict__ w, __bf16* __restrict__ dst,
                         int Cin, int ksq)
{
    const int total = 256 * Cin * ksq;
    const int idx = blockIdx.x * 256 + threadIdx.x;
    if (idx >= total) return;
    const int o = idx / (Cin * ksq);
    const int r = idx - o * (Cin * ksq);
    const int c = r / ksq;
    const int sh = r - c * ksq;
    dst[((size_t)sh * 256 + o) * Cin + c] = (__bf16)w[idx];
}

// ---------------------------------------------------------------------------
// SPE = support lateral + PE (bf16): spe[sb][c][l] = s[sb][c][l] + peT[c][l]
__global__ void addpe_kernel(const bf16* __restrict__ s, const float* __restrict__ peT,
                             bf16* __restrict__ spe, int L, int total)
{
    const int idx = blockIdx.x * 256 + threadIdx.x;
    if (idx >= total) return;
    const int l = idx % L;
    const int c = (idx / L) & 255;
    spe[idx] = __float2bfloat16(__bfloat162float(s[idx]) + peT[(size_t)c * 1600 + l]);
}

// ---------------------------------------------------------------------------
__global__ void bias_init_kernel(float* __restrict__ out, const float* __restrict__ bias,
                                 int N, int total)
{
    const int idx = blockIdx.x * 256 + threadIdx.x;
    if (idx >= total) return;
    out[idx] = bias[(idx / N) & 255];
}

__global__ void cast_f32_bf16(const float* __restrict__ src, bf16* __restrict__ dst,
                              int total)
{
    const int idx = blockIdx.x * 256 + threadIdx.x;
    if (idx < total) dst[idx] = __float2bfloat16(src[idx]);
}

// ---------------------------------------------------------------------------
// 1x1 GEMM (MFMA). out_mode: 0 = f32 d-major, 1 = bf16 d-major, 2 = bf16 row-major.
__global__ __launch_bounds__(256)
void gemm1x1_mfma(const void* __restrict__ in, const __bf16* __restrict__ wbf,
                  const float* __restrict__ bias, void* __restrict__ out,
                  int Cin, int N, int in_bf16, int out_mode)
{
    const int b  = blockIdx.z;
    const int o0 = blockIdx.y * 64;
    const int n0 = blockIdx.x * 64;
    const int t  = threadIdx.x;
    const int wv  = t >> 6;
    const int ln  = t & 63;
    const int lm  = ln & 15;
    const int kq8 = (ln >> 4) * 8;

    __shared__ __bf16 Bs[64][LK];

    f32x4 acc[4];
    #pragma unroll
    for (int ct = 0; ct < 4; ++ct) acc[ct] = (f32x4){0.f, 0.f, 0.f, 0.f};

    const int cg = t >> 4;
    const int ng = t & 15;
    const int nb = n0 + ng * 4;
    const bool vec_ok = ((N & 3) == 0) && (nb + 3 < N);

    const float*  inf = (const float*)in;
    const __bf16* inh = (const __bf16*)in;
    const size_t inb0 = (size_t)b * Cin * N;

    const __bf16* arow = wbf + (size_t)(o0 + wv * 16 + lm) * Cin;

    for (int c0 = 0; c0 < Cin; c0 += 64) {
        __syncthreads();
        float rv[4][4];
        #pragma unroll
        for (int i = 0; i < 4; ++i) {
            const int c = c0 + cg * 4 + i;
            const size_t base = inb0 + (size_t)c * N + nb;
            if (vec_ok) {
                if (in_bf16) {
                    const bf16x4v v = *(const bf16x4v*)&inh[base];
                    rv[i][0] = (float)v[0]; rv[i][1] = (float)v[1];
                    rv[i][2] = (float)v[2]; rv[i][3] = (float)v[3];
                } else {
                    const float4 v = *(const float4*)&inf[base];
                    rv[i][0] = v.x; rv[i][1] = v.y; rv[i][2] = v.z; rv[i][3] = v.w;
                }
            } else {
                #pragma unroll
                for (int jj = 0; jj < 4; ++jj) {
                    const int n = nb + jj;
                    rv[i][jj] = (n < N) ? (in_bf16 ? (float)inh[inb0 + (size_t)c * N + n]
                                                   : inf[inb0 + (size_t)c * N + n])
                                        : 0.f;
                }
            }
        }
        #pragma unroll
        for (int jj = 0; jj < 4; ++jj) {
            bf16x4v pk;
            pk[0] = (__bf16)rv[0][jj]; pk[1] = (__bf16)rv[1][jj];
            pk[2] = (__bf16)rv[2][jj]; pk[3] = (__bf16)rv[3][jj];
            *(bf16x4v*)&Bs[ng * 4 + jj][cg * 4] = pk;
        }
        __syncthreads();

        #pragma unroll
        for (int k0 = 0; k0 < 64; k0 += 32) {
            const bf16x8 a = *(const bf16x8*)&arow[c0 + k0 + kq8];
            #pragma unroll
            for (int ct = 0; ct < 4; ++ct) {
                const bf16x8 bb = *(const bf16x8*)&Bs[ct * 16 + lm][k0 + kq8];
                acc[ct] = __builtin_amdgcn_mfma_f32_16x16x32_bf16(a, bb, acc[ct], 0, 0, 0);
            }
        }
    }

    const int rbase = o0 + wv * 16 + (ln >> 4) * 4;
    #pragma unroll
    for (int ct = 0; ct < 4; ++ct) {
        const int col = n0 + ct * 16 + lm;
        if (col < N) {
            if (out_mode == 2) {
                bf16x4v pk;
                #pragma unroll
                for (int r = 0; r < 4; ++r)
                    pk[r] = (__bf16)(acc[ct][r] + bias[rbase + r]);
                *(bf16x4v*)&((__bf16*)out)[((size_t)b * N + col) * 256 + rbase] = pk;
            } else {
                const size_t outb = (size_t)b * 256 * N;
                #pragma unroll
                for (int r = 0; r < 4; ++r) {
                    const int o = rbase + r;
                    const float val = acc[ct][r] + bias[o];
                    if (out_mode == 1) ((__bf16*)out)[outb + (size_t)o * N + col] = (__bf16)val;
                    else               ((float*)out)[outb + (size_t)o * N + col] = val;
                }
            }
        }
    }
}

// ---------------------------------------------------------------------------
// 3x3 stride-1 pad-1 conv (MFMA) with HALO tile.
__global__ __launch_bounds__(256)
void conv3x3h_mfma(const void* __restrict__ in, const __bf16* __restrict__ wbf,
                   const float* __restrict__ bias, void* __restrict__ out,
                   const float* __restrict__ addup,
                   int Cin, int H, int W, int in_bf16, int out_bf16)
{
    const int b  = blockIdx.z;
    const int o0 = blockIdx.y * 64;
    const int n0 = blockIdx.x * 64;
    const int N  = H * W;
    const int EXT = 64 + 2 * W + 2;
    const int t  = threadIdx.x;
    const int wv = t >> 6;
    const int ln = t & 63;
    const int lm = ln & 15;
    const int kq8 = (ln >> 4) * 8;

    __shared__ __bf16 Bs[146][LK];

    f32x4 acc[4];
    #pragma unroll
    for (int ct = 0; ct < 4; ++ct) acc[ct] = (f32x4){0.f, 0.f, 0.f, 0.f};

    const size_t inb0 = (size_t)b * Cin * N;
    const int upH = H >> 1, upW = W >> 1;
    const float* addb = addup ? addup + (size_t)b * Cin * upH * upW : nullptr;
    const float*  inf = (const float*)in;
    const __bf16* inh = (const __bf16*)in;

    int yct[4], xct[4];
    bool nok[4];
    #pragma unroll
    for (int ct = 0; ct < 4; ++ct) {
        const int n = n0 + ct * 16 + lm;
        nok[ct] = n < N;
        yct[ct] = nok[ct] ? n / W : 0;
        xct[ct] = nok[ct] ? n - yct[ct] * W : 0;
    }

    bf16x8 zro;
    #pragma unroll
    for (int j = 0; j < 8; ++j) zro[j] = (__bf16)0.f;

    const int srow = t & 63;
    const int kb16 = (t >> 6) * 16;
    const int basep = n0 - W - 1;

    for (int c0 = 0; c0 < Cin; c0 += 64) {
        __syncthreads();
        for (int rb = 0; rb < EXT; rb += 64) {
            const int row = rb + srow;
            if (row < EXT) {
                const int p = basep + row;
                const bool ok = (p >= 0) && (p < N);
                const int py = ok ? p / W : 0;
                const int px = ok ? p - py * W : 0;
                #pragma unroll
                for (int j = 0; j < 16; ++j) {
                    const int kk = kb16 + j;
                    const int c  = c0 + kk;
                    float v = 0.f;
                    if (ok) {
                        v = in_bf16 ? (float)inh[inb0 + (size_t)c * N + p]
                                    : inf[inb0 + (size_t)c * N + p];
                        if (addb) v += addb[((size_t)c * upH + (py >> 1)) * upW + (px >> 1)];
                    }
                    Bs[row][kk] = (__bf16)v;
                }
            }
        }
        __syncthreads();

        #pragma unroll
        for (int sh = 0; sh < 9; ++sh) {
            const int ky = sh / 3, kx = sh - ky * 3;
            const int off = (ky - 1) * W + (kx - 1) + W + 1;
            bool vm[4];
            #pragma unroll
            for (int ct = 0; ct < 4; ++ct)
                vm[ct] = nok[ct] && (unsigned)(yct[ct] + ky - 1) < (unsigned)H
                                 && (unsigned)(xct[ct] + kx - 1) < (unsigned)W;
            const __bf16* ash = wbf + ((size_t)sh * 256 + o0 + wv * 16 + lm) * Cin + c0;
            #pragma unroll
            for (int k0 = 0; k0 < 64; k0 += 32) {
                const bf16x8 a = *(const bf16x8*)&ash[k0 + kq8];
                #pragma unroll
                for (int ct = 0; ct < 4; ++ct) {
                    bf16x8 bb = *(const bf16x8*)&Bs[ct * 16 + lm + off][k0 + kq8];
                    bb = vm[ct] ? bb : zro;
                    acc[ct] = __builtin_amdgcn_mfma_f32_16x16x32_bf16(a, bb, acc[ct], 0, 0, 0);
                }
            }
        }
    }

    const size_t outb = (size_t)b * 256 * N;
    const int rbase = o0 + wv * 16 + (ln >> 4) * 4;
    #pragma unroll
    for (int ct = 0; ct < 4; ++ct) {
        const int col = n0 + ct * 16 + lm;
        if (col < N) {
            #pragma unroll
            for (int r = 0; r < 4; ++r) {
                const int o = rbase + r;
                const float val = acc[ct][r] + bias[o];
                if (out_bf16) ((__bf16*)out)[outb + (size_t)o * N + col] = (__bf16)val;
                else          ((float*)out)[outb + (size_t)o * N + col] = val;
            }
        }
    }
}

// ---------------------------------------------------------------------------
// Split-K, batch-packed conv (tiny-N / huge-K: P6, P7).
__global__ __launch_bounds__(256)
void convsk_mfma(const void* __restrict__ in, const __bf16* __restrict__ wbf,
                 float* __restrict__ out,
                 int B, int Cin, int Hin, int Win, int Ho, int Wo,
                 int ks, int stride, int pad, int relu_in, int in_bf16,
                 int kchunk)
{
    const int N  = Ho * Wo;
    const int NT = B * N;
    const int col0 = blockIdx.x * 64;
    const int t  = threadIdx.x;
    const int wv = t >> 6;
    const int ln = t & 63;
    const int lm = ln & 15;
    const int kq8 = (ln >> 4) * 8;

    __shared__ __bf16 Bs[64][LK];

    f32x4 acc[4][4];
    #pragma unroll
    for (int rt = 0; rt < 4; ++rt)
        #pragma unroll
        for (int ct = 0; ct < 4; ++ct) acc[rt][ct] = (f32x4){0.f, 0.f, 0.f, 0.f};

    const size_t inHW = (size_t)Hin * Win;
    const int ksq = ks * ks;
    const float*  inf = (const float*)in;
    const __bf16* inh = (const __bf16*)in;

    const int srow = t & 63;
    const int kb16 = (t >> 6) * 16;
    const int scol = col0 + srow;
    const bool cvalid = scol < NT;
    int sb = 0, yo = 0, xo = 0;
    if (cvalid) {
        sb = scol / N;
        const int sn = scol - sb * N;
        yo = sn / Wo; xo = sn - yo * Wo;
    }

    const int Ktot = Cin * ksq;
    const int kbeg = blockIdx.y * kchunk;
    const int kend = min(kbeg + kchunk, Ktot);

    for (int k0 = kbeg; k0 < kend; k0 += 64) {
        const int sh = k0 / Cin;
        const int c0 = k0 - sh * Cin;
        const int ky = sh / ks, kx = sh - ky * ks;
        const int iy = yo * stride + ky - pad;
        const int ix = xo * stride + kx - pad;
        const bool ld_ok = cvalid && iy >= 0 && iy < Hin && ix >= 0 && ix < Win;
        const size_t sidx = (size_t)sb * Cin * inHW + (size_t)iy * Win + ix;

        __syncthreads();
        #pragma unroll
        for (int j = 0; j < 16; ++j) {
            const int kk = kb16 + j;
            const int c  = c0 + kk;
            float v = 0.f;
            if (ld_ok) {
                v = in_bf16 ? (float)inh[sidx + (size_t)c * inHW]
                            : inf[sidx + (size_t)c * inHW];
                if (relu_in) v = fmaxf(v, 0.f);
            }
            Bs[srow][kk] = (__bf16)v;
        }
        __syncthreads();

        #pragma unroll
        for (int k32 = 0; k32 < 64; k32 += 32) {
            bf16x8 bfr[4];
            #pragma unroll
            for (int ct = 0; ct < 4; ++ct)
                bfr[ct] = *(const bf16x8*)&Bs[ct * 16 + lm][k32 + kq8];
            #pragma unroll
            for (int rt = 0; rt < 4; ++rt) {
                const __bf16* ap = wbf + ((size_t)sh * 256 + wv * 64 + rt * 16 + lm) * Cin
                                       + c0 + k32 + kq8;
                const bf16x8 a = *(const bf16x8*)ap;
                #pragma unroll
                for (int ct = 0; ct < 4; ++ct)
                    acc[rt][ct] = __builtin_amdgcn_mfma_f32_16x16x32_bf16(a, bfr[ct],
                                                                          acc[rt][ct], 0, 0, 0);
            }
        }
    }

    const int rb0 = wv * 64 + (ln >> 4) * 4;
    #pragma unroll
    for (int ct = 0; ct < 4; ++ct) {
        const int col = col0 + ct * 16 + lm;
        if (col < NT) {
            const int be = col / N;
            const int ne = col - be * N;
            float* ob = out + (size_t)be * 256 * N + ne;
            #pragma unroll
            for (int rt = 0; rt < 4; ++rt)
                #pragma unroll
                for (int r = 0; r < 4; ++r)
                    atomicAdd(&ob[(size_t)(rb0 + rt * 16 + r) * N], acc[rt][ct][r]);
        }
    }
}

// ---------------------------------------------------------------------------
__global__ void add_up_kernel(const float* __restrict__ a, const float* __restrict__ up,
                              float* __restrict__ o, int H, int W, int total)
{
    const int idx = blockIdx.x * 256 + threadIdx.x;
    if (idx >= total) return;
    const int x = idx % W;
    const int tmp = idx / W;
    const int y = tmp % H;
    const int bc = tmp / H;
    o[idx] = a[idx] + up[((size_t)bc * (H >> 1) + (y >> 1)) * (W >> 1) + (x >> 1)];
}

// ---------------------------------------------------------------------------
// MFMA flash attention — r14 configuration (best measured: 536us @ L=1600,
// total 2052us; reproduced twice). Block = (64 q, b, s); 4 waves x 16 q-rows.
__global__ __launch_bounds__(256)
void attn_mfma(const __bf16* __restrict__ Qrow, const __bf16* __restrict__ Krow,
               const bf16* __restrict__ Sv, float* __restrict__ outp, int L, int S)
{
    const int b  = blockIdx.y;
    const int s  = blockIdx.z;
    const int q0 = blockIdx.x * 64;
    const int t  = threadIdx.x;
    const int wv = t >> 6;
    const int ln = t & 63;
    const int lm = ln & 15;
    const int lg = ln >> 4;

    __shared__ __bf16 Ks[32][264];
    __shared__ __bf16 Vt[256][40];
    __shared__ __bf16 Pl[4][16][40];

    bf16x8 qf[8];
    {
        const int q = q0 + wv * 16 + lm;
        if (q < L) {
            const __bf16* qp = Qrow + ((size_t)b * L + q) * 256 + lg * 8;
            #pragma unroll
            for (int sl = 0; sl < 8; ++sl) qf[sl] = *(const bf16x8*)&qp[sl * 32];
        } else {
            #pragma unroll
            for (int sl = 0; sl < 8; ++sl)
                #pragma unroll
                for (int j = 0; j < 8; ++j) qf[sl][j] = (__bf16)0.f;
        }
    }

    f32x4 acc[16];
    #pragma unroll
    for (int ds = 0; ds < 16; ++ds) acc[ds] = (f32x4){0.f, 0.f, 0.f, 0.f};
    float m_run[4] = {-INFINITY, -INFINITY, -INFINITY, -INFINITY};
    float l_run[4] = {0.f, 0.f, 0.f, 0.f};

    const size_t kbase = (size_t)(b * S + s) * L * 256;
    const __bf16* vb0  = (const __bf16*)Sv + (size_t)(b * S + s) * 256 * L;

    const int nt = (L + 31) >> 5;
    for (int lt = 0; lt < nt; ++lt) {
        const int l0 = lt << 5;
        __syncthreads();
        {
            const int row = t >> 3, cb = (t & 7) * 32;
            const int l = l0 + row;
            if (l < L) {
                const __bf16* src = Krow + kbase + (size_t)l * 256 + cb;
                #pragma unroll
                for (int j = 0; j < 4; ++j)
                    *(bf16x8*)&Ks[row][cb + j * 8] = *(const bf16x8*)&src[j * 8];
            } else {
                #pragma unroll
                for (int j = 0; j < 32; ++j) Ks[row][cb + j] = (__bf16)0.f;
            }
        }
        {
            const __bf16* src = vb0 + (size_t)t * L + l0;
            if (l0 + 32 <= L && ((((size_t)src) & 15) == 0)) {
                #pragma unroll
                for (int j = 0; j < 4; ++j)
                    *(bf16x8*)&Vt[t][j * 8] = *(const bf16x8*)&src[j * 8];
            } else {
                #pragma unroll
                for (int j = 0; j < 32; ++j)
                    Vt[t][j] = (l0 + j < L) ? src[j] : (__bf16)0.f;
            }
        }
        __syncthreads();

        f32x4 sc0 = (f32x4){0.f, 0.f, 0.f, 0.f};
        f32x4 sc1 = (f32x4){0.f, 0.f, 0.f, 0.f};
        #pragma unroll
        for (int sl = 0; sl < 8; ++sl) {
            const bf16x8 k0 = *(const bf16x8*)&Ks[lm][sl * 32 + lg * 8];
            const bf16x8 k1 = *(const bf16x8*)&Ks[16 + lm][sl * 32 + lg * 8];
            sc0 = __builtin_amdgcn_mfma_f32_16x16x32_bf16(qf[sl], k0, sc0, 0, 0, 0);
            sc1 = __builtin_amdgcn_mfma_f32_16x16x32_bf16(qf[sl], k1, sc1, 0, 0, 0);
        }

        const bool v0 = (l0 + lm) < L;
        const bool v1 = (l0 + 16 + lm) < L;
        float p0[4], p1[4], mt[4];
        #pragma unroll
        for (int r = 0; r < 4; ++r) {
            const float a = v0 ? sc0[r] * 0.0625f : -INFINITY;
            const float c = v1 ? sc1[r] * 0.0625f : -INFINITY;
            p0[r] = a; p1[r] = c; mt[r] = fmaxf(a, c);
        }
        #pragma unroll
        for (int w = 1; w < 16; w <<= 1)
            #pragma unroll
            for (int r = 0; r < 4; ++r) mt[r] = fmaxf(mt[r], __shfl_xor(mt[r], w, 16));
        float alpha[4], rs[4];
        #pragma unroll
        for (int r = 0; r < 4; ++r) {
            const float mn = fmaxf(m_run[r], mt[r]);
            alpha[r] = __expf(m_run[r] - mn);
            p0[r] = v0 ? __expf(p0[r] - mn) : 0.f;
            p1[r] = v1 ? __expf(p1[r] - mn) : 0.f;
            m_run[r] = mn;
            rs[r] = p0[r] + p1[r];
        }
        #pragma unroll
        for (int w = 1; w < 16; w <<= 1)
            #pragma unroll
            for (int r = 0; r < 4; ++r) rs[r] += __shfl_xor(rs[r], w, 16);
        #pragma unroll
        for (int r = 0; r < 4; ++r) l_run[r] = l_run[r] * alpha[r] + rs[r];
        #pragma unroll
        for (int ds = 0; ds < 16; ++ds)
            #pragma unroll
            for (int r = 0; r < 4; ++r) acc[ds][r] *= alpha[r];

        #pragma unroll
        for (int r = 0; r < 4; ++r) {
            Pl[wv][lg * 4 + r][lm]      = (__bf16)p0[r];
            Pl[wv][lg * 4 + r][16 + lm] = (__bf16)p1[r];
        }
        const bf16x8 pa = *(const bf16x8*)&Pl[wv][lm][lg * 8];

        #pragma unroll
        for (int ds = 0; ds < 16; ++ds) {
            const bf16x8 vv = *(const bf16x8*)&Vt[ds * 16 + lm][lg * 8];
            acc[ds] = __builtin_amdgcn_mfma_f32_16x16x32_bf16(pa, vv, acc[ds], 0, 0, 0);
        }
    }

    const int qrow = q0 + wv * 16 + lg * 4;
    float inv[4];
    #pragma unroll
    for (int r = 0; r < 4; ++r) inv[r] = 1.f / (l_run[r] * (float)S);
    #pragma unroll
    for (int ds = 0; ds < 16; ++ds) {
        const int d = ds * 16 + lm;
        float* ob = outp + ((size_t)b * 512 + 256 + d) * L;
        #pragma unroll
        for (int r = 0; r < 4; ++r) {
            const int q = qrow + r;
            if (q < L) atomicAdd(&ob[q], acc[ds][r] * inv[r]);
        }
    }
}

// ---------------------------------------------------------------------------
__global__ void zero_attn_half(float* __restrict__ outp, int L, int total)
{
    const int idx = blockIdx.x * 256 + threadIdx.x;
    if (idx >= total) return;
    const int b = idx / (256 * L);
    const int r = idx - b * 256 * L;
    outp[((size_t)b * 512 + 256) * L + r] = 0.f;
}

// ---------------------------------------------------------------------------
__global__ void copy_cast_kernel(const void* __restrict__ src, float* __restrict__ dst,
                                 int HW, int total, int in_bf16)
{
    const int idx = blockIdx.x * 256 + threadIdx.x;
    if (idx >= total) return;
    const int b = idx / (256 * HW);
    const int r = idx - b * 256 * HW;
    const float v = in_bf16 ? __bfloat162float(((const bf16*)src)[idx])
                            : ((const float*)src)[idx];
    dst[(size_t)b * 512 * HW + r] = v;
}

// ---------------------------------------------------------------------------
extern "C" void kernel_launch(void* const* d_in, const int* in_sizes, int n_in,
                              void* d_out, int out_size, void* d_ws, size_t ws_size,
                              hipStream_t stream)
{
    (void)in_sizes; (void)n_in; (void)out_size; (void)ws_size;
    const float* C3 = (const float*)d_in[0];
    const float* C4 = (const float*)d_in[1];
    const float* C5 = (const float*)d_in[2];
    const float* S3 = (const float*)d_in[3];
    const float* S4 = (const float*)d_in[4];
    const float* S5 = (const float*)d_in[5];
    const float* p31w = (const float*)d_in[6];  const float* p31b = (const float*)d_in[7];
    const float* p32w = (const float*)d_in[8];  const float* p32b = (const float*)d_in[9];
    const float* p41w = (const float*)d_in[10]; const float* p41b = (const float*)d_in[11];
    const float* p42w = (const float*)d_in[12]; const float* p42b = (const float*)d_in[13];
    const float* p51w = (const float*)d_in[14]; const float* p51b = (const float*)d_in[15];
    const float* p52w = (const float*)d_in[16]; const float* p52b = (const float*)d_in[17];
    const float* p6w  = (const float*)d_in[18]; const float* p6b  = (const float*)d_in[19];
    const float* p7w  = (const float*)d_in[20]; const float* p7b  = (const float*)d_in[21];
    const float* qw   = (const float*)d_in[22]; const float* qb   = (const float*)d_in[23];
    const float* kw   = (const float*)d_in[24]; const float* kb   = (const float*)d_in[25];
    float* out = (float*)d_out;

    // ---- workspace layout (bytes, 256B-aligned). ~165 MB.
    uint8_t* base = (uint8_t*)d_ws;
    size_t off = 0;
    auto A = [&](size_t bytes) { size_t r = off; off += (bytes + 255) & ~(size_t)255; return r; };
    float* pPE  = (float*)(base + A((size_t)256 * 1600 * 4));           // peT[d][l]
    bf16*  pP3q = (bf16*) (base + A((size_t)8  * 256 * 1600 * 2));
    float* pP4q = (float*)(base + A((size_t)8  * 256 * 400  * 4));
    float* pP5q = (float*)(base + A((size_t)8  * 256 * 100  * 4));
    bf16*  pP3s = (bf16*) (base + A((size_t)40 * 256 * 1600 * 2));
    bf16*  pP4s = (bf16*) (base + A((size_t)40 * 256 * 400  * 2));
    bf16*  pP5s = (bf16*) (base + A((size_t)40 * 256 * 100  * 2));
    float* pP6q = (float*)(base + A((size_t)8  * 256 * 25   * 4));
    float* pP7q = (float*)(base + A((size_t)8  * 256 * 9    * 4));
    float* pP6sF= (float*)(base + A((size_t)40 * 256 * 25   * 4));
    float* pP7sF= (float*)(base + A((size_t)40 * 256 * 9    * 4));
    bf16*  pP6s = (bf16*) (base + A((size_t)40 * 256 * 25   * 2));
    bf16*  pP7s = (bf16*) (base + A((size_t)40 * 256 * 9    * 2));
    float* pP4m = (float*)(base + A((size_t)8  * 256 * 400  * 4));
    float* pP5f = (float*)(base + A((size_t)8  * 256 * 100  * 4));
    float* pP4f = (float*)(base + A((size_t)8  * 256 * 400  * 4));
    bf16*  pP3f = (bf16*) (base + A((size_t)8  * 256 * 1600 * 2));
    __bf16* pQ  = (__bf16*)(base + A((size_t)8  * 1600 * 256 * 2));   // row-major [b][q][256]
    __bf16* pK  = (__bf16*)(base + A((size_t)40 * 1600 * 256 * 2));   // row-major [sb][l][256]
    bf16*  pSPE = (bf16*) (base + A((size_t)40 * 256 * 1600 * 2));    // d-major
    __bf16* r31 = (__bf16*)(base + A((size_t)256 * 512 * 2));
    __bf16* r32 = (__bf16*)(base + A((size_t)256 * 256 * 9 * 2));
    __bf16* r41 = (__bf16*)(base + A((size_t)256 * 1024 * 2));
    __bf16* r42 = (__bf16*)(base + A((size_t)256 * 256 * 9 * 2));
    __bf16* r51 = (__bf16*)(base + A((size_t)256 * 2048 * 2));
    __bf16* r52 = (__bf16*)(base + A((size_t)256 * 256 * 9 * 2));
    __bf16* r6  = (__bf16*)(base + A((size_t)256 * 2048 * 9 * 2));
    __bf16* r7  = (__bf16*)(base + A((size_t)256 * 256 * 9 * 2));
    __bf16* rq  = (__bf16*)(base + A((size_t)256 * 256 * 2));
    __bf16* rk  = (__bf16*)(base + A((size_t)256 * 256 * 2));

    pe_init_kernel<<<dim3(256), dim3(256), 0, stream>>>(pPE);

    auto rep = [&](const float* w, __bf16* dst, int Cin, int ksq) {
        const int total = 256 * Cin * ksq;
        repack_w<<<dim3((total + 255) / 256), dim3(256), 0, stream>>>(w, dst, Cin, ksq);
    };
    rep(p31w, r31, 512, 1);  rep(p32w, r32, 256, 9);
    rep(p41w, r41, 1024, 1); rep(p42w, r42, 256, 9);
    rep(p51w, r51, 2048, 1); rep(p52w, r52, 256, 9);
    rep(p6w,  r6,  2048, 9); rep(p7w,  r7,  256, 9);
    rep(qw,   rq,  256, 1);  rep(kw,   rk,  256, 1);

    auto g1 = [&](const void* in, const __bf16* wbf, const float* bias, void* o,
                  int B, int Cin, int N, int in_bf16, int out_mode) {
        dim3 g((N + 63) / 64, 4, B);
        gemm1x1_mfma<<<g, dim3(256), 0, stream>>>(in, wbf, bias, o, Cin, N,
                                                  in_bf16, out_mode);
    };
    auto ch3 = [&](const void* in, const __bf16* wbf, const float* bias, void* o,
                   int B, int Cin, int H, int W, const float* addup,
                   int in_bf16, int out_bf16) {
        const int N = H * W;
        dim3 g((N + 63) / 64, 4, B);
        conv3x3h_mfma<<<g, dim3(256), 0, stream>>>(in, wbf, bias, o, addup,
                                                   Cin, H, W, in_bf16, out_bf16);
    };
    auto csk = [&](const void* in, const __bf16* wbf, const float* bias, float* o,
                   int B, int Cin, int Hin, int Win, int Ho, int Wo,
                   int stride, int pad, int relu_in, int in_bf16, int kchunk) {
        const int N = Ho * Wo;
        const int NT = B * N;
        const int Ktot = Cin * 9;
        const int total = B * 256 * N;
        bias_init_kernel<<<dim3((total + 255) / 256), dim3(256), 0, stream>>>(
            o, bias, N, total);
        dim3 g((NT + 63) / 64, (Ktot + kchunk - 1) / kchunk, 1);
        convsk_mfma<<<g, dim3(256), 0, stream>>>(in, wbf, o, B, Cin, Hin, Win, Ho, Wo,
                                                 3, stride, pad, relu_in, in_bf16, kchunk);
    };

    // lateral 1x1 convs
    g1(C3, r31, p31b, pP3q, 8,  512,  1600, 0, 1);
    g1(C4, r41, p41b, pP4q, 8,  1024, 400,  0, 0);
    g1(C5, r51, p51b, pP5q, 8,  2048, 100,  0, 0);
    g1(S3, r31, p31b, pP3s, 40, 512,  1600, 0, 1);
    g1(S4, r41, p41b, pP4s, 40, 1024, 400,  0, 1);
    g1(S5, r51, p51b, pP5s, 40, 2048, 100,  0, 1);
    // P6 / P7 via split-K packed kernel
    csk(C5,    r6, p6b, pP6q,  8,  2048, 10, 10, 5, 5, 2, 1, 0, 0, 576);
    csk(S5,    r6, p6b, pP6sF, 40, 2048, 10, 10, 5, 5, 2, 1, 0, 0, 1152);
    {
        const int t6 = 40 * 256 * 25;
        cast_f32_bf16<<<dim3((t6 + 255) / 256), dim3(256), 0, stream>>>(pP6sF, pP6s, t6);
    }
    csk(pP6q,  r7, p7b, pP7q,  8,  256, 5, 5, 3, 3, 2, 1, 1, 0, 576);
    csk(pP6sF, r7, p7b, pP7sF, 40, 256, 5, 5, 3, 3, 2, 1, 1, 0, 576);
    {
        const int t7 = 40 * 256 * 9;
        cast_f32_bf16<<<dim3((t7 + 255) / 256), dim3(256), 0, stream>>>(pP7sF, pP7s, t7);
    }
    // top-down
    {
        const int total = 8 * 256 * 400;
        add_up_kernel<<<dim3((total + 255) / 256), dim3(256), 0, stream>>>(
            pP4q, pP5q, pP4m, 20, 20, total);
    }
    ch3(pP5q, r52, p52b, pP5f, 8, 256, 10, 10, nullptr, 0, 0);
    ch3(pP4m, r42, p42b, pP4f, 8, 256, 20, 20, nullptr, 0, 0);
    ch3(pP3q, r32, p32b, pP3f, 8, 256, 40, 40, pP4m, 1, 1);

    const int Ls[5] = {1600, 400, 100, 25, 9};
    const void* qsrc[5] = {pP3f, pP4f, pP5f, pP6q, pP7q};
    const int   qbf [5] = {1, 0, 0, 0, 0};
    const bf16* ssrc[5] = {pP3s, pP4s, pP5s, pP6s, pP7s};
    size_t ooff[5];
    {
        size_t ao = 0;
        for (int i = 0; i < 5; ++i) { ooff[i] = ao; ao += (size_t)8 * 512 * Ls[i]; }
    }
    for (int i = 0; i < 5; ++i) {
        const int L = Ls[i];
        const int stotal = 40 * 256 * L;
        addpe_kernel<<<dim3((stotal + 255) / 256), dim3(256), 0, stream>>>(
            ssrc[i], pPE, pSPE, L, stotal);
        g1(qsrc[i], rq, qb, pQ, 8, 256, L, qbf[i], 2);
        g1(pSPE, rk, kb, pK, 40, 256, L, 1, 2);
        const int total = 8 * 256 * L;
        zero_attn_half<<<dim3((total + 255) / 256), dim3(256), 0, stream>>>(
            out + ooff[i], L, total);
        attn_mfma<<<dim3((L + 63) / 64, 8, 5), dim3(256), 0, stream>>>(
            pQ, pK, pSPE, out + ooff[i], L, 5);
        copy_cast_kernel<<<dim3((total + 255) / 256), dim3(256), 0, stream>>>(
            qsrc[i], out + ooff[i], L, total, qbf[i]);
    }
}